// Round 2
// baseline (2497.844 us; speedup 1.0000x reference)
//
#include <hip/hip_runtime.h>
#include <hip/hip_bf16.h>

// ConvLSTM (2 layers) on MI355X. R13: dead-K removal (CS 160->128) + tap-packed x MFMA.
// - Fusion reverted (R12 regressed: 2048 blocks = exactly 4 full rounds, no tail to fill).
// - LDS XOR swizzle kept (conflicts 5.9M -> 98K, proven correct).
// - P (B,64,64,128) fp16 = pure h0, 256 B/pixel. 4 staging chunks/row (was 5): -20%
//   DMA + LDS reads + B fetches, -18% MFMA work.
// - x contribution via Xtap[t][pix][16] (9 tap-shifted x values, k=taps): one extra
//   K=32 MFMA set per block; B zeros for k>=16 via zero page (A needs no masking).
// - h1 in separate H1[2] (pix,16ch) buffer; gg1 consumes it via 9-tap K16-in-K32 phase
//   with an 8448B mini-halo. All MFMAs remain 16x16x32_f16.
// Geometry: 256-thr blocks, wave tile 64x64 (gg0) / 64x48 (gg1), acc 4x4 / 2x3,
// LDS dbuf 33792 (+8448 gg1), 1-tap B register prefetch, DMA halo staging.

typedef __attribute__((ext_vector_type(8))) short short8;
typedef __attribute__((ext_vector_type(4))) float float4v;

#define CS 128
#define KT0 1152          // 9*128

__device__ __forceinline__ float sigf(float x) { return 1.f / (1.f + __expf(-x)); }
__device__ __forceinline__ short f2hs(float v) {
  _Float16 h = (_Float16)v;
  return *(short*)&h;
}
__device__ __forceinline__ float bs2f(short s) {
  __hip_bfloat16 h; *(short*)&h = s; return __bfloat162float(h);
}
__device__ __forceinline__ short f2bs(float v) {
  __hip_bfloat16 h = __float2bfloat16(v);
  return *(short*)&h;
}

// async 16B global->LDS; per-lane lds ptr must equal uniform_base + lane*16
__device__ __forceinline__ void async_ld16(const short* g, short* l) {
  __builtin_amdgcn_global_load_lds(
      (const __attribute__((address_space(1))) unsigned int*)g,
      (__attribute__((address_space(3))) unsigned int*)l, 16, 0, 0);
}

// Stage one halo row (66 px x 32 ch) into LDS at dstRow (row-major, 32ch/px).
// XOR swizzle: LDS slot (px,v) receives ch-group v^((px>>1)&3), applied via permuted
// global SOURCE (DMA dest must stay linear). DMA key = (lane>>3)&3; tail key(64/65)=0.
__device__ __forceinline__ void stage_row(const short* __restrict__ rowPtr, bool rowOK,
                                          short* dstRow, int lane,
                                          const short* __restrict__ zp) {
  int vs8 = (((lane & 3) ^ ((lane >> 3) & 3)) << 3);
  #pragma unroll
  for (int j = 0; j < 4; ++j) {
    int e = j * 64 + lane;
    int px = e >> 2;
    int xx = px - 1;
    const short* g = (rowOK && xx >= 0) ? (rowPtr + (size_t)xx * CS + vs8) : zp;
    async_ld16(g, dstRow + e * 8);
  }
  if (lane < 8) {
    int px = 64 + (lane >> 2), v = lane & 3, xx = px - 1;
    short8 val = {0, 0, 0, 0, 0, 0, 0, 0};
    if (rowOK && xx < 64) val = *(const short8*)(rowPtr + (size_t)xx * CS + v * 8);
    *(short8*)(dstRow + px * 32 + v * 8) = val;
  }
}

// Stage one h1 halo row (66 px x 16 ch) at dstRow (1056 shorts). No swizzle (minor path).
__device__ __forceinline__ void stage_h1(const short* __restrict__ rowPtr, bool rowOK,
                                         short* dstRow, int lane,
                                         const short* __restrict__ zp) {
  #pragma unroll
  for (int j = 0; j < 2; ++j) {
    int e = j * 64 + lane;
    int px = e >> 1, h = e & 1, xx = px - 1;
    const short* g = (rowOK && xx >= 0) ? (rowPtr + (size_t)xx * 16 + h * 8) : zp;
    async_ld16(g, dstRow + e * 8);
  }
  if (lane < 4) {
    int px = 64 + (lane >> 1), h = lane & 1, xx = px - 1;
    short8 val = {0, 0, 0, 0, 0, 0, 0, 0};
    if (rowOK && xx < 64) val = *(const short8*)(rowPtr + (size_t)xx * 16 + h * 8);
    *(short8*)(dstRow + px * 16 + h * 8) = val;
  }
}

// ---- dtype detect: fp32 low-halves have uniform bits[14:7]; bf16 weights cluster ----
__global__ void detect_dtype(const unsigned short* __restrict__ w0, int* __restrict__ flag) {
  int lane = threadIdx.x;
  int cnt = 0;
  for (int i = 0; i < 4; ++i) {
    unsigned short u = w0[2 * (lane + 64 * i)];
    int e = (u >> 7) & 0xFF;
    unsigned long long b = __ballot(e >= 0xC0);
    cnt += __popcll(b);
  }
  if (lane == 0) *flag = (cnt > 32) ? 1 : 0;   // 1 = fp32 inputs
}

__global__ void canon_b(const void* __restrict__ b0, const void* __restrict__ b1,
                        float* __restrict__ Bc0, float* __restrict__ Bc1,
                        const int* __restrict__ flag) {
  int i = blockIdx.x * 256 + threadIdx.x;
  int fl = *flag;
  if (i < 512) {
    float v = fl ? ((const float*)b0)[i] : bs2f(((const short*)b0)[i]);
    if (!isfinite(v) || fabsf(v) > 1e4f) v = 0.f;
    Bc0[i] = v;
  } else if (i < 560) {
    int j = i - 512;
    float v = fl ? ((const float*)b1)[j] : bs2f(((const short*)b1)[j]);
    if (!isfinite(v) || fabsf(v) > 1e4f) v = 0.f;
    Bc1[j] = v;
  }
}

__device__ __forceinline__ float ldw(const void* W, int idx, int fl) {
  float w = fl ? ((const float*)W)[idx] : bs2f(((const short*)W)[idx]);
  if (!isfinite(w) || fabsf(w) > 1e4f) w = 0.f;
  return w;
}

// layer0 h0 weights: Wp0[co][tap*128+c] = W0[co][1+c][tap]  (512 x 1152)
__global__ void prep_w0(const void* __restrict__ W0, short* __restrict__ Wp,
                        const int* __restrict__ flag) {
  int i = blockIdx.x * 256 + threadIdx.x;
  if (i >= 512 * KT0) return;
  int fl = *flag;
  int co = i / KT0, k = i - co * KT0;
  int tap = k >> 7, c = k & 127;
  Wp[i] = f2hs(ldw(W0, (co * 129 + 1 + c) * 9 + tap, fl));
}

// layer0 x weights: Wx[co][16], k<9 -> W0[co][0][k], else 0  (512 x 16)
__global__ void prep_wx(const void* __restrict__ W0, short* __restrict__ Wx,
                        const int* __restrict__ flag) {
  int i = blockIdx.x * 256 + threadIdx.x;
  if (i >= 512 * 16) return;
  int fl = *flag;
  int co = i >> 4, k = i & 15;
  float w = (k < 9) ? ldw(W0, (co * 129) * 9 + k, fl) : 0.f;
  Wx[i] = f2hs(w);
}

// layer1 h0 weights: Wp1[co][tap*128+c] = W1[co][c][tap]  (48 x 1152)
__global__ void prep_w1(const void* __restrict__ W1, short* __restrict__ Wp,
                        const int* __restrict__ flag) {
  int i = blockIdx.x * 256 + threadIdx.x;
  if (i >= 48 * KT0) return;
  int fl = *flag;
  int co = i / KT0, k = i - co * KT0;
  int tap = k >> 7, c = k & 127;
  Wp[i] = f2hs(ldw(W1, (co * 140 + c) * 9 + tap, fl));
}

// layer1 h1 weights: Wh[co][tap*16+kk], kk<12 -> W1[co][128+kk][tap], else 0  (48 x 144)
__global__ void prep_wh(const void* __restrict__ W1, short* __restrict__ Wh,
                        const int* __restrict__ flag) {
  int i = blockIdx.x * 256 + threadIdx.x;
  if (i >= 48 * 144) return;
  int fl = *flag;
  int co = i / 144, k = i - co * 144;
  int tap = k >> 4, kk = k & 15;
  float w = (kk < 12) ? ldw(W1, (co * 140 + 128 + kk) * 9 + tap, fl) : 0.f;
  Wh[i] = f2hs(w);
}

// Xtap[t][p][16]: k<9 = sanitized x[t] at tap-shifted pixel (0 at borders), k>=9 = 0.
// p = b*4096 + y*64 + x ; hist is (B=16, L=12, 4096, 1).
__global__ void prep_xtap(const void* __restrict__ hist, short* __restrict__ Xtap,
                          const int* __restrict__ flag) {
  int i = blockIdx.x * 256 + threadIdx.x;      // < 786432 = 12*65536
  int t = i >> 16, p = i & 65535;
  int b = p >> 12, pix = p & 4095, y = pix >> 6, x = pix & 63;
  int fl = *flag;
  short8 lo = {0, 0, 0, 0, 0, 0, 0, 0}, hi = {0, 0, 0, 0, 0, 0, 0, 0};
  #pragma unroll
  for (int k = 0; k < 9; ++k) {
    int dy = k / 3, dx = k - dy * 3;
    int yy = y + dy - 1, xx = x + dx - 1;
    float f = 0.f;
    if (yy >= 0 && yy < 64 && xx >= 0 && xx < 64) {
      int hidx = (b * 12 + t) * 4096 + yy * 64 + xx;
      f = fl ? ((const float*)hist)[hidx] : bs2f(((const short*)hist)[hidx]);
      if (!isfinite(f) || fabsf(f) > 1e4f) f = 0.f;
    }
    if (k < 8) lo[k] = f2hs(f); else hi[k - 8] = f2hs(f);
  }
  *(short8*)(Xtap + (size_t)i * 16) = lo;
  *(short8*)(Xtap + (size_t)i * 16 + 8) = hi;
}

// ---- layer 0: M=128px (2 rows) x N=128co (4 gates x 32 hc). Grid = 4 nt * 512 mt. ----
__global__ __launch_bounds__(256, 2) void gemm_gate0(
    const short* __restrict__ Pcur, short* __restrict__ Pnext,
    const short* __restrict__ Wp, const short* __restrict__ Wx,
    const float* __restrict__ Bc0, float* __restrict__ C0,
    const short* __restrict__ Xtap, const short* __restrict__ zp, int t) {
  int bx = blockIdx.x;
  int nt = bx >> 9, mt = bx & 511;             // consecutive blocks share nt (weight L2 reuse)
  int b = mt >> 5, y0 = (mt & 31) * 2;
  int tid = threadIdx.x, wave = tid >> 6, lane = tid & 63;
  int ln15 = lane & 15, quad = lane >> 4;
  int wm = wave & 1, wn = wave >> 1;
  int hc = nt * 32 + wn * 16 + ln15;

  __shared__ __align__(16) short halo[2 * 4 * 66 * 32];   // dbuf, 33792 B

  float4v acc[4][4];
  #pragma unroll
  for (int i = 0; i < 4; ++i)
    #pragma unroll
    for (int j = 0; j < 4; ++j) acc[i][j] = (float4v){0.f, 0.f, 0.f, 0.f};

  const short* wbase = Wp + (size_t)hc * KT0 + quad * 8;
  short8 bcur[4], bnxt[4];
  #pragma unroll
  for (int g = 0; g < 4; ++g)
    bcur[g] = *(const short8*)(wbase + (size_t)g * 128 * KT0);

  int yy = y0 - 1 + wave;
  bool rowOK = (yy >= 0) && (yy < 64);
  const short* rowBase = Pcur + (size_t)((b * 64 + yy) * 64) * CS;
  int rowPix = (b * 64 + y0 + wm) * 64;

  stage_row(rowBase, rowOK, halo + wave * 2112, lane, zp);

  // x tap-chunk: K=32 MFMA, k=taps (0..8 live). A = Xtap (no masking needed);
  // B = Wx for quads 0/1, zero page for quads 2/3 (kills k>=16 products).
  {
    bool hiQ = quad >= 2;
    const short* xb = Xtap + ((size_t)t * 65536 + rowPix + ln15) * 16 + (quad & 1) * 8;
    short8 ax[4], bx[4];
    #pragma unroll
    for (int mf = 0; mf < 4; ++mf) ax[mf] = *(const short8*)(xb + mf * 256);
    #pragma unroll
    for (int g = 0; g < 4; ++g) {
      const short* wxp = Wx + (size_t)(g * 128 + hc) * 16 + (quad & 1) * 8;
      bx[g] = *(const short8*)(hiQ ? zp : wxp);
    }
    #pragma unroll
    for (int g = 0; g < 4; ++g)
      #pragma unroll
      for (int mf = 0; mf < 4; ++mf)
        acc[mf][g] = __builtin_amdgcn_mfma_f32_16x16x32_f16(ax[mf], bx[g], acc[mf][g], 0, 0, 0);
  }
  __syncthreads();

  for (int ch = 0; ch < 4; ++ch) {
    int c0 = ch * 32;
    const short* cur = halo + (ch & 1) * 8448;
    if (ch < 3)
      stage_row(rowBase + c0 + 32, rowOK, halo + ((ch + 1) & 1) * 8448 + wave * 2112,
                lane, zp);
    #pragma unroll
    for (int tap = 0; tap < 9; ++tap) {
      int dy = tap / 3, dx = tap - dy * 3;
      int ntap = (tap < 8) ? tap + 1 : 0;
      int nc0 = (tap < 8) ? c0 : ((ch < 3) ? c0 + 32 : c0);
      #pragma unroll
      for (int g = 0; g < 4; ++g)
        bnxt[g] = *(const short8*)(wbase + (size_t)g * 128 * KT0 + ntap * 128 + nc0);

      int qs = (quad ^ (((ln15 + dx) >> 1) & 3)) * 8;   // swizzled slot
      short8 af[4];
      #pragma unroll
      for (int mf = 0; mf < 4; ++mf)
        af[mf] = *(const short8*)&cur[((wm + dy) * 66 + mf * 16 + ln15 + dx) * 32 + qs];
      #pragma unroll
      for (int g = 0; g < 4; ++g)
        #pragma unroll
        for (int mf = 0; mf < 4; ++mf)
          acc[mf][g] = __builtin_amdgcn_mfma_f32_16x16x32_f16(af[mf], bcur[g], acc[mf][g], 0, 0, 0);
      #pragma unroll
      for (int g = 0; g < 4; ++g) bcur[g] = bnxt[g];
    }
    __syncthreads();
  }

  // epilogue: all 4 gates in-register per (pix,hc)
  float bi = Bc0[hc], bff = Bc0[128 + hc], bo = Bc0[256 + hc], bg = Bc0[384 + hc];
  #pragma unroll
  for (int mf = 0; mf < 4; ++mf) {
    #pragma unroll
    for (int r = 0; r < 4; ++r) {
      int x = mf * 16 + quad * 4 + r;          // C/D row = quad*4 + reg
      int pix = rowPix + x;
      float zi = acc[mf][0][r] + bi;
      float zf = acc[mf][1][r] + bff;
      float zo = acc[mf][2][r] + bo;
      float zg = acc[mf][3][r] + bg;
      float cprev = C0[(size_t)pix * 128 + hc];
      float cn = sigf(zf) * cprev + sigf(zi) * tanhf(zg);
      float hn = sigf(zo) * tanhf(cn);
      C0[(size_t)pix * 128 + hc] = cn;
      Pnext[(size_t)pix * CS + hc] = f2hs(hn);
    }
  }
}

// ---- layer 1: M=128px (2 rows) x N=48co. Grid 512. h0 4 chunks + h1 tap phase. ----
__global__ __launch_bounds__(256, 2) void gemm_gate1(
    const short* __restrict__ Prd, const short* __restrict__ H1rd,
    short* __restrict__ H1wr, const short* __restrict__ Wp,
    const short* __restrict__ Wh, const float* __restrict__ Bc1,
    float* __restrict__ C1, void* __restrict__ outp,
    const short* __restrict__ zp, const int* __restrict__ flagp, int t) {
  int bid = blockIdx.x;                        // 0..511
  int b = bid >> 5, y0 = (bid & 31) * 2;
  int tid = threadIdx.x, wave = tid >> 6, lane = tid & 63;
  int ln15 = lane & 15, quad = lane >> 4;
  int wr = wave >> 1, wh = wave & 1;
  int flagv = *flagp;

  __shared__ __align__(16) short halo[2 * 4 * 66 * 32];   // 33792 B
  __shared__ __align__(16) short h1h[4 * 66 * 16];        // 8448 B

  float4v acc[2][3];
  #pragma unroll
  for (int i = 0; i < 2; ++i)
    #pragma unroll
    for (int j = 0; j < 3; ++j) acc[i][j] = (float4v){0.f, 0.f, 0.f, 0.f};

  int yy = y0 - 1 + wave;
  bool rowOK = (yy >= 0) && (yy < 64);
  const short* rowBase = Prd + (size_t)((b * 64 + yy) * 64) * CS;
  const short* h1Base = H1rd + (size_t)((b * 64 + yy) * 64) * 16;

  const short* wbase = Wp + (size_t)ln15 * KT0 + quad * 8;
  short8 bcur[3], bnxt[3];
  #pragma unroll
  for (int nf = 0; nf < 3; ++nf)
    bcur[nf] = *(const short8*)(wbase + (size_t)nf * 16 * KT0);

  stage_row(rowBase, rowOK, halo + wave * 2112, lane, zp);
  stage_h1(h1Base, rowOK, h1h + wave * 1056, lane, zp);
  __syncthreads();

  for (int ch = 0; ch < 4; ++ch) {
    int c0 = ch * 32;
    const short* cur = halo + (ch & 1) * 8448;
    if (ch < 3)
      stage_row(rowBase + c0 + 32, rowOK, halo + ((ch + 1) & 1) * 8448 + wave * 2112,
                lane, zp);
    #pragma unroll
    for (int tap = 0; tap < 9; ++tap) {
      int dy = tap / 3, dx = tap - dy * 3;
      int ntap = (tap < 8) ? tap + 1 : 0;
      int nc0 = (tap < 8) ? c0 : ((ch < 3) ? c0 + 32 : c0);
      #pragma unroll
      for (int nf = 0; nf < 3; ++nf)
        bnxt[nf] = *(const short8*)(wbase + (size_t)nf * 16 * KT0 + ntap * 128 + nc0);

      int qs = (quad ^ (((ln15 + dx) >> 1) & 3)) * 8;
      short8 af[2];
      #pragma unroll
      for (int mf = 0; mf < 2; ++mf)
        af[mf] = *(const short8*)&cur[((wr + dy) * 66 + wh * 32 + mf * 16 + ln15 + dx) * 32
                                      + qs];
      #pragma unroll
      for (int nf = 0; nf < 3; ++nf)
        #pragma unroll
        for (int mf = 0; mf < 2; ++mf)
          acc[mf][nf] = __builtin_amdgcn_mfma_f32_16x16x32_f16(af[mf], bcur[nf], acc[mf][nf], 0, 0, 0);
      #pragma unroll
      for (int nf = 0; nf < 3; ++nf) bcur[nf] = bnxt[nf];
    }
    __syncthreads();
  }

  // h1 tap phase: K=32 MFMA, ch k=0..15 from mini-halo (12 live); B zero for k>=16
  // via zero page, so A needs no masking.
  {
    bool hiQ = quad >= 2;
    #pragma unroll
    for (int tap = 0; tap < 9; ++tap) {
      int dy = tap / 3, dx = tap - dy * 3;
      short8 bh[3];
      #pragma unroll
      for (int nf = 0; nf < 3; ++nf) {
        const short* whp = Wh + (size_t)((nf * 16 + ln15) * 9 + tap) * 16 + (quad & 1) * 8;
        bh[nf] = *(const short8*)(hiQ ? zp : whp);
      }
      short8 ah[2];
      #pragma unroll
      for (int mf = 0; mf < 2; ++mf)
        ah[mf] = *(const short8*)&h1h[((wr + dy) * 66 + wh * 32 + mf * 16 + ln15 + dx) * 16
                                      + (quad & 1) * 8];
      #pragma unroll
      for (int nf = 0; nf < 3; ++nf)
        #pragma unroll
        for (int mf = 0; mf < 2; ++mf)
          acc[mf][nf] = __builtin_amdgcn_mfma_f32_16x16x32_f16(ah[mf], bh[nf], acc[mf][nf], 0, 0, 0);
    }
  }
  __syncthreads();

  // z -> LDS (reuse halo; stride 49 avoids 4-way bank conflict), then gate pass
  float* zbuf = (float*)halo;
  #pragma unroll
  for (int mf = 0; mf < 2; ++mf)
    #pragma unroll
    for (int nf = 0; nf < 3; ++nf)
      #pragma unroll
      for (int r = 0; r < 4; ++r) {
        int pxl = wr * 64 + wh * 32 + mf * 16 + quad * 4 + r;
        zbuf[pxl * 49 + nf * 16 + ln15] = acc[mf][nf][r];
      }
  __syncthreads();

  #pragma unroll
  for (int k = 0; k < 6; ++k) {
    int id = k * 256 + tid;
    int hc = id >> 7, pxl = id & 127;
    float zi = zbuf[pxl * 49 + hc]      + Bc1[hc];
    float zf = zbuf[pxl * 49 + 12 + hc] + Bc1[12 + hc];
    float zo = zbuf[pxl * 49 + 24 + hc] + Bc1[24 + hc];
    float zg = zbuf[pxl * 49 + 36 + hc] + Bc1[36 + hc];
    int y = y0 + (pxl >> 6), x = pxl & 63;
    int pix = (b * 64 + y) * 64 + x;
    float cprev = C1[(size_t)pix * 12 + hc];
    float cn = sigf(zf) * cprev + sigf(zi) * tanhf(zg);
    float hn = sigf(zo) * tanhf(cn);
    C1[(size_t)pix * 12 + hc] = cn;
    H1wr[(size_t)pix * 16 + hc] = f2hs(hn);
    if (t == 11) {
      int oidx = (b * 12 + hc) * 4096 + y * 64 + x;
      if (flagv) ((float*)outp)[oidx] = hn;
      else ((short*)outp)[oidx] = f2bs(hn);
    }
  }
}

extern "C" void kernel_launch(void* const* d_in, const int* in_sizes, int n_in,
                              void* d_out, int out_size, void* d_ws, size_t ws_size,
                              hipStream_t stream) {
  const void* hist = d_in[0];                  // (16,12,4096,1)
  const void* W0 = d_in[2];                    // (512,129,3,3)
  const void* b0 = d_in[3];
  const void* W1 = d_in[4];                    // (48,140,3,3)
  const void* b1 = d_in[5];

  char* ws = (char*)d_ws;
  const size_t PszB = (size_t)16 * 4096 * CS * 2;     // 16,777,216
  short* P[2] = {(short*)ws, (short*)(ws + PszB)};
  float* C0 = (float*)(ws + 2 * PszB);                // 33,554,432
  const size_t C0e = 2 * PszB + 33554432;
  float* C1 = (float*)(ws + C0e);                     // 3,145,728
  const size_t C1e = C0e + 3145728;
  const size_t H1szB = (size_t)16 * 4096 * 16 * 2;    // 2,097,152
  short* H1[2] = {(short*)(ws + C1e), (short*)(ws + C1e + H1szB)};
  const size_t H1e = C1e + 2 * H1szB;
  short* zp = (short*)(ws + H1e);                     // 256 B zero page
  const size_t zpe = H1e + 256;                       // 74,449,152 -> memset to here
  short* Xtap = (short*)(ws + zpe);                   // 12*65536*16*2 = 25,165,824
  const size_t Xte = zpe + (size_t)12 * 65536 * 16 * 2;
  short* Wp0 = (short*)(ws + Xte);                    // 512*1152*2 = 1,179,648
  const size_t W0e = Xte + (size_t)512 * KT0 * 2;
  short* Wx0 = (short*)(ws + W0e);                    // 512*16*2 = 16,384
  const size_t Wxe = W0e + 512 * 16 * 2;
  short* Wp1 = (short*)(ws + Wxe);                    // 48*1152*2 = 110,592
  const size_t W1e = Wxe + (size_t)48 * KT0 * 2;
  short* Wh1 = (short*)(ws + W1e);                    // 48*144*2 = 13,824
  const size_t Whe = W1e + 48 * 144 * 2;
  float* Bc0 = (float*)(ws + Whe);                    // 2048
  float* Bc1 = (float*)(ws + Whe + 2048);             // 192
  int* flag = (int*)(ws + Whe + 2048 + 192);          // total ~101 MiB

  hipMemsetAsync(ws, 0, zpe, stream);                 // P pair + C0 + C1 + H1 pair + zp
  detect_dtype<<<1, 64, 0, stream>>>((const unsigned short*)W0, flag);
  canon_b<<<3, 256, 0, stream>>>(b0, b1, Bc0, Bc1, flag);
  prep_w0<<<(512 * KT0 + 255) / 256, 256, 0, stream>>>(W0, Wp0, flag);
  prep_wx<<<32, 256, 0, stream>>>(W0, Wx0, flag);
  prep_w1<<<(48 * KT0 + 255) / 256, 256, 0, stream>>>(W1, Wp1, flag);
  prep_wh<<<27, 256, 0, stream>>>(W1, Wh1, flag);
  prep_xtap<<<3072, 256, 0, stream>>>(hist, Xtap, flag);

  for (int t = 0; t < 12; ++t) {
    gemm_gate0<<<2048, 256, 0, stream>>>(P[t & 1], P[(t + 1) & 1], Wp0, Wx0, Bc0, C0,
                                         Xtap, zp, t);
    gemm_gate1<<<512, 256, 0, stream>>>(P[(t + 1) & 1], H1[(t + 1) & 1], H1[t & 1],
                                        Wp1, Wh1, Bc1, C1, d_out, zp, flag, t);
  }
}

// Round 3
// 2485.943 us; speedup vs baseline: 1.0048x; 1.0048x over previous
//
#include <hip/hip_runtime.h>
#include <hip/hip_bf16.h>

// ConvLSTM (2 layers) on MI355X. R14: R13's dead-K removal kept; occupancy recovered.
// - LDS XOR swizzle REMOVED (R12/R13 post-mortem: +12 VGPR -> occupancy 30%->22%,
//   pace -40%; conflict elimination bought nothing in this latency-bound regime).
// - x-chunk operand loads hoisted BEFORE halo DMA (in-order vmcnt: consuming them no
//   longer drains the staging queue; x-MFMAs overlap DMA).
// - XCD-chunked block swizzle (2048=8*256, 512=8*64, bijective): adjacent mt blocks
//   (sharing halo rows + weight slice) land on the same XCD L2.
// - __launch_bounds__(256,3) pins allocator to 3-wave/SIMD budget.
// Structure: P (B,64,64,128) fp16 = pure h0 (256 B/px, 4 chunks/row); x via
// Xtap[t][pix][16] tap-packed K=32 MFMA (B zeros for k>=16 via zero page);
// h1 in separate H1[2] (pix,16ch), consumed via 9-tap K16-in-K32 phase w/ mini-halo.
// Geometry: 256-thr blocks, wave tile 64x64 (gg0) / 64x48 (gg1), acc 4x4 / 2x3,
// LDS dbuf 33792 (+8448 gg1), 1-tap B register prefetch, DMA halo staging.

typedef __attribute__((ext_vector_type(8))) short short8;
typedef __attribute__((ext_vector_type(4))) float float4v;

#define CS 128
#define KT0 1152          // 9*128

__device__ __forceinline__ float sigf(float x) { return 1.f / (1.f + __expf(-x)); }
__device__ __forceinline__ short f2hs(float v) {
  _Float16 h = (_Float16)v;
  return *(short*)&h;
}
__device__ __forceinline__ float bs2f(short s) {
  __hip_bfloat16 h; *(short*)&h = s; return __bfloat162float(h);
}
__device__ __forceinline__ short f2bs(float v) {
  __hip_bfloat16 h = __float2bfloat16(v);
  return *(short*)&h;
}

// async 16B global->LDS; per-lane lds ptr must equal uniform_base + lane*16
__device__ __forceinline__ void async_ld16(const short* g, short* l) {
  __builtin_amdgcn_global_load_lds(
      (const __attribute__((address_space(1))) unsigned int*)g,
      (__attribute__((address_space(3))) unsigned int*)l, 16, 0, 0);
}

// Stage one halo row (66 px x 32 ch) into LDS at dstRow (row-major, 32ch/px). Linear.
__device__ __forceinline__ void stage_row(const short* __restrict__ rowPtr, bool rowOK,
                                          short* dstRow, int lane,
                                          const short* __restrict__ zp) {
  #pragma unroll
  for (int j = 0; j < 4; ++j) {
    int e = j * 64 + lane;
    int px = e >> 2, v = e & 3;
    int xx = px - 1;
    const short* g = (rowOK && xx >= 0) ? (rowPtr + (size_t)xx * CS + v * 8) : zp;
    async_ld16(g, dstRow + e * 8);
  }
  if (lane < 8) {
    int px = 64 + (lane >> 2), v = lane & 3, xx = px - 1;
    short8 val = {0, 0, 0, 0, 0, 0, 0, 0};
    if (rowOK && xx < 64) val = *(const short8*)(rowPtr + (size_t)xx * CS + v * 8);
    *(short8*)(dstRow + px * 32 + v * 8) = val;
  }
}

// Stage one h1 halo row (66 px x 16 ch) at dstRow (1056 shorts).
__device__ __forceinline__ void stage_h1(const short* __restrict__ rowPtr, bool rowOK,
                                         short* dstRow, int lane,
                                         const short* __restrict__ zp) {
  #pragma unroll
  for (int j = 0; j < 2; ++j) {
    int e = j * 64 + lane;
    int px = e >> 1, h = e & 1, xx = px - 1;
    const short* g = (rowOK && xx >= 0) ? (rowPtr + (size_t)xx * 16 + h * 8) : zp;
    async_ld16(g, dstRow + e * 8);
  }
  if (lane < 4) {
    int px = 64 + (lane >> 1), h = lane & 1, xx = px - 1;
    short8 val = {0, 0, 0, 0, 0, 0, 0, 0};
    if (rowOK && xx < 64) val = *(const short8*)(rowPtr + (size_t)xx * 16 + h * 8);
    *(short8*)(dstRow + px * 16 + h * 8) = val;
  }
}

// ---- dtype detect: fp32 low-halves have uniform bits[14:7]; bf16 weights cluster ----
__global__ void detect_dtype(const unsigned short* __restrict__ w0, int* __restrict__ flag) {
  int lane = threadIdx.x;
  int cnt = 0;
  for (int i = 0; i < 4; ++i) {
    unsigned short u = w0[2 * (lane + 64 * i)];
    int e = (u >> 7) & 0xFF;
    unsigned long long b = __ballot(e >= 0xC0);
    cnt += __popcll(b);
  }
  if (lane == 0) *flag = (cnt > 32) ? 1 : 0;   // 1 = fp32 inputs
}

__global__ void canon_b(const void* __restrict__ b0, const void* __restrict__ b1,
                        float* __restrict__ Bc0, float* __restrict__ Bc1,
                        const int* __restrict__ flag) {
  int i = blockIdx.x * 256 + threadIdx.x;
  int fl = *flag;
  if (i < 512) {
    float v = fl ? ((const float*)b0)[i] : bs2f(((const short*)b0)[i]);
    if (!isfinite(v) || fabsf(v) > 1e4f) v = 0.f;
    Bc0[i] = v;
  } else if (i < 560) {
    int j = i - 512;
    float v = fl ? ((const float*)b1)[j] : bs2f(((const short*)b1)[j]);
    if (!isfinite(v) || fabsf(v) > 1e4f) v = 0.f;
    Bc1[j] = v;
  }
}

__device__ __forceinline__ float ldw(const void* W, int idx, int fl) {
  float w = fl ? ((const float*)W)[idx] : bs2f(((const short*)W)[idx]);
  if (!isfinite(w) || fabsf(w) > 1e4f) w = 0.f;
  return w;
}

// layer0 h0 weights: Wp0[co][tap*128+c] = W0[co][1+c][tap]  (512 x 1152)
__global__ void prep_w0(const void* __restrict__ W0, short* __restrict__ Wp,
                        const int* __restrict__ flag) {
  int i = blockIdx.x * 256 + threadIdx.x;
  if (i >= 512 * KT0) return;
  int fl = *flag;
  int co = i / KT0, k = i - co * KT0;
  int tap = k >> 7, c = k & 127;
  Wp[i] = f2hs(ldw(W0, (co * 129 + 1 + c) * 9 + tap, fl));
}

// layer0 x weights: Wx[co][16], k<9 -> W0[co][0][k], else 0  (512 x 16)
__global__ void prep_wx(const void* __restrict__ W0, short* __restrict__ Wx,
                        const int* __restrict__ flag) {
  int i = blockIdx.x * 256 + threadIdx.x;
  if (i >= 512 * 16) return;
  int fl = *flag;
  int co = i >> 4, k = i & 15;
  float w = (k < 9) ? ldw(W0, (co * 129) * 9 + k, fl) : 0.f;
  Wx[i] = f2hs(w);
}

// layer1 h0 weights: Wp1[co][tap*128+c] = W1[co][c][tap]  (48 x 1152)
__global__ void prep_w1(const void* __restrict__ W1, short* __restrict__ Wp,
                        const int* __restrict__ flag) {
  int i = blockIdx.x * 256 + threadIdx.x;
  if (i >= 48 * KT0) return;
  int fl = *flag;
  int co = i / KT0, k = i - co * KT0;
  int tap = k >> 7, c = k & 127;
  Wp[i] = f2hs(ldw(W1, (co * 140 + c) * 9 + tap, fl));
}

// layer1 h1 weights: Wh[co][tap*16+kk], kk<12 -> W1[co][128+kk][tap], else 0  (48 x 144)
__global__ void prep_wh(const void* __restrict__ W1, short* __restrict__ Wh,
                        const int* __restrict__ flag) {
  int i = blockIdx.x * 256 + threadIdx.x;
  if (i >= 48 * 144) return;
  int fl = *flag;
  int co = i / 144, k = i - co * 144;
  int tap = k >> 4, kk = k & 15;
  float w = (kk < 12) ? ldw(W1, (co * 140 + 128 + kk) * 9 + tap, fl) : 0.f;
  Wh[i] = f2hs(w);
}

// Xtap[t][p][16]: k<9 = sanitized x[t] at tap-shifted pixel (0 at borders), k>=9 = 0.
__global__ void prep_xtap(const void* __restrict__ hist, short* __restrict__ Xtap,
                          const int* __restrict__ flag) {
  int i = blockIdx.x * 256 + threadIdx.x;      // < 786432 = 12*65536
  int t = i >> 16, p = i & 65535;
  int b = p >> 12, pix = p & 4095, y = pix >> 6, x = pix & 63;
  int fl = *flag;
  short8 lo = {0, 0, 0, 0, 0, 0, 0, 0}, hi = {0, 0, 0, 0, 0, 0, 0, 0};
  #pragma unroll
  for (int k = 0; k < 9; ++k) {
    int dy = k / 3, dx = k - dy * 3;
    int yy = y + dy - 1, xx = x + dx - 1;
    float f = 0.f;
    if (yy >= 0 && yy < 64 && xx >= 0 && xx < 64) {
      int hidx = (b * 12 + t) * 4096 + yy * 64 + xx;
      f = fl ? ((const float*)hist)[hidx] : bs2f(((const short*)hist)[hidx]);
      if (!isfinite(f) || fabsf(f) > 1e4f) f = 0.f;
    }
    if (k < 8) lo[k] = f2hs(f); else hi[k - 8] = f2hs(f);
  }
  *(short8*)(Xtap + (size_t)i * 16) = lo;
  *(short8*)(Xtap + (size_t)i * 16 + 8) = hi;
}

// ---- layer 0: M=128px (2 rows) x N=128co (4 gates x 32 hc). Grid = 4 nt * 512 mt. ----
__global__ __launch_bounds__(256, 3) void gemm_gate0(
    const short* __restrict__ Pcur, short* __restrict__ Pnext,
    const short* __restrict__ Wp, const short* __restrict__ Wx,
    const float* __restrict__ Bc0, float* __restrict__ C0,
    const short* __restrict__ Xtap, const short* __restrict__ zp, int t) {
  // XCD-chunked swizzle: hw round-robins blockIdx%8 across XCDs; give each XCD a
  // contiguous 256-block logical range (same nt, adjacent mt -> halo rows + weight
  // slice L2-hot). 2048 % 8 == 0 -> bijective.
  int pbx = blockIdx.x;
  int wg = (pbx & 7) * 256 + (pbx >> 3);
  int nt = wg >> 9, mt = wg & 511;
  int b = mt >> 5, y0 = (mt & 31) * 2;
  int tid = threadIdx.x, wave = tid >> 6, lane = tid & 63;
  int ln15 = lane & 15, quad = lane >> 4;
  int wm = wave & 1, wn = wave >> 1;
  int hc = nt * 32 + wn * 16 + ln15;

  __shared__ __align__(16) short halo[2 * 4 * 66 * 32];   // dbuf, 33792 B

  float4v acc[4][4];
  #pragma unroll
  for (int i = 0; i < 4; ++i)
    #pragma unroll
    for (int j = 0; j < 4; ++j) acc[i][j] = (float4v){0.f, 0.f, 0.f, 0.f};

  const short* wbase = Wp + (size_t)hc * KT0 + quad * 8;
  short8 bcur[4], bnxt[4];
  #pragma unroll
  for (int g = 0; g < 4; ++g)
    bcur[g] = *(const short8*)(wbase + (size_t)g * 128 * KT0);

  int yy = y0 - 1 + wave;
  bool rowOK = (yy >= 0) && (yy < 64);
  const short* rowBase = Pcur + (size_t)((b * 64 + yy) * 64) * CS;
  int rowPix = (b * 64 + y0 + wm) * 64;

  // x tap-chunk operand loads issued BEFORE the halo DMA: consuming them then needs
  // only vmcnt<=16 (DMA issued after stays in flight under the x MFMAs).
  short8 ax[4], bxr[4];
  {
    bool hiQ = quad >= 2;
    const short* xb = Xtap + ((size_t)t * 65536 + rowPix + ln15) * 16 + (quad & 1) * 8;
    #pragma unroll
    for (int mf = 0; mf < 4; ++mf) ax[mf] = *(const short8*)(xb + mf * 256);
    #pragma unroll
    for (int g = 0; g < 4; ++g) {
      const short* wxp = Wx + (size_t)(g * 128 + hc) * 16 + (quad & 1) * 8;
      bxr[g] = *(const short8*)(hiQ ? zp : wxp);
    }
  }

  stage_row(rowBase, rowOK, halo + wave * 2112, lane, zp);

  // x tap-chunk: K=32 MFMA, k=taps (0..8 live); B zeros for k>=16 via zero page.
  #pragma unroll
  for (int g = 0; g < 4; ++g)
    #pragma unroll
    for (int mf = 0; mf < 4; ++mf)
      acc[mf][g] = __builtin_amdgcn_mfma_f32_16x16x32_f16(ax[mf], bxr[g], acc[mf][g], 0, 0, 0);
  __syncthreads();

  for (int ch = 0; ch < 4; ++ch) {
    int c0 = ch * 32;
    const short* cur = halo + (ch & 1) * 8448;
    if (ch < 3)
      stage_row(rowBase + c0 + 32, rowOK, halo + ((ch + 1) & 1) * 8448 + wave * 2112,
                lane, zp);
    #pragma unroll
    for (int tap = 0; tap < 9; ++tap) {
      int dy = tap / 3, dx = tap - dy * 3;
      int ntap = (tap < 8) ? tap + 1 : 0;
      int nc0 = (tap < 8) ? c0 : ((ch < 3) ? c0 + 32 : c0);
      #pragma unroll
      for (int g = 0; g < 4; ++g)
        bnxt[g] = *(const short8*)(wbase + (size_t)g * 128 * KT0 + ntap * 128 + nc0);

      short8 af[4];
      #pragma unroll
      for (int mf = 0; mf < 4; ++mf)
        af[mf] = *(const short8*)&cur[((wm + dy) * 66 + mf * 16 + ln15 + dx) * 32 + quad * 8];
      #pragma unroll
      for (int g = 0; g < 4; ++g)
        #pragma unroll
        for (int mf = 0; mf < 4; ++mf)
          acc[mf][g] = __builtin_amdgcn_mfma_f32_16x16x32_f16(af[mf], bcur[g], acc[mf][g], 0, 0, 0);
      #pragma unroll
      for (int g = 0; g < 4; ++g) bcur[g] = bnxt[g];
    }
    __syncthreads();
  }

  // epilogue: all 4 gates in-register per (pix,hc)
  float bi = Bc0[hc], bff = Bc0[128 + hc], bo = Bc0[256 + hc], bg = Bc0[384 + hc];
  #pragma unroll
  for (int mf = 0; mf < 4; ++mf) {
    #pragma unroll
    for (int r = 0; r < 4; ++r) {
      int x = mf * 16 + quad * 4 + r;          // C/D row = quad*4 + reg
      int pix = rowPix + x;
      float zi = acc[mf][0][r] + bi;
      float zf = acc[mf][1][r] + bff;
      float zo = acc[mf][2][r] + bo;
      float zg = acc[mf][3][r] + bg;
      float cprev = C0[(size_t)pix * 128 + hc];
      float cn = sigf(zf) * cprev + sigf(zi) * tanhf(zg);
      float hn = sigf(zo) * tanhf(cn);
      C0[(size_t)pix * 128 + hc] = cn;
      Pnext[(size_t)pix * CS + hc] = f2hs(hn);
    }
  }
}

// ---- layer 1: M=128px (2 rows) x N=48co. Grid 512. h0 4 chunks + h1 tap phase. ----
__global__ __launch_bounds__(256, 2) void gemm_gate1(
    const short* __restrict__ Prd, const short* __restrict__ H1rd,
    short* __restrict__ H1wr, const short* __restrict__ Wp,
    const short* __restrict__ Wh, const float* __restrict__ Bc1,
    float* __restrict__ C1, void* __restrict__ outp,
    const short* __restrict__ zp, const int* __restrict__ flagp, int t) {
  int pbx = blockIdx.x;                        // 512 = 8*64, bijective XCD chunking
  int bid = (pbx & 7) * 64 + (pbx >> 3);
  int b = bid >> 5, y0 = (bid & 31) * 2;
  int tid = threadIdx.x, wave = tid >> 6, lane = tid & 63;
  int ln15 = lane & 15, quad = lane >> 4;
  int wr = wave >> 1, wh = wave & 1;
  int flagv = *flagp;

  __shared__ __align__(16) short halo[2 * 4 * 66 * 32];   // 33792 B
  __shared__ __align__(16) short h1h[4 * 66 * 16];        // 8448 B

  float4v acc[2][3];
  #pragma unroll
  for (int i = 0; i < 2; ++i)
    #pragma unroll
    for (int j = 0; j < 3; ++j) acc[i][j] = (float4v){0.f, 0.f, 0.f, 0.f};

  int yy = y0 - 1 + wave;
  bool rowOK = (yy >= 0) && (yy < 64);
  const short* rowBase = Prd + (size_t)((b * 64 + yy) * 64) * CS;
  const short* h1Base = H1rd + (size_t)((b * 64 + yy) * 64) * 16;

  const short* wbase = Wp + (size_t)ln15 * KT0 + quad * 8;
  short8 bcur[3], bnxt[3];
  #pragma unroll
  for (int nf = 0; nf < 3; ++nf)
    bcur[nf] = *(const short8*)(wbase + (size_t)nf * 16 * KT0);

  stage_row(rowBase, rowOK, halo + wave * 2112, lane, zp);
  stage_h1(h1Base, rowOK, h1h + wave * 1056, lane, zp);
  __syncthreads();

  for (int ch = 0; ch < 4; ++ch) {
    int c0 = ch * 32;
    const short* cur = halo + (ch & 1) * 8448;
    if (ch < 3)
      stage_row(rowBase + c0 + 32, rowOK, halo + ((ch + 1) & 1) * 8448 + wave * 2112,
                lane, zp);
    #pragma unroll
    for (int tap = 0; tap < 9; ++tap) {
      int dy = tap / 3, dx = tap - dy * 3;
      int ntap = (tap < 8) ? tap + 1 : 0;
      int nc0 = (tap < 8) ? c0 : ((ch < 3) ? c0 + 32 : c0);
      #pragma unroll
      for (int nf = 0; nf < 3; ++nf)
        bnxt[nf] = *(const short8*)(wbase + (size_t)nf * 16 * KT0 + ntap * 128 + nc0);

      short8 af[2];
      #pragma unroll
      for (int mf = 0; mf < 2; ++mf)
        af[mf] = *(const short8*)&cur[((wr + dy) * 66 + wh * 32 + mf * 16 + ln15 + dx) * 32
                                      + quad * 8];
      #pragma unroll
      for (int nf = 0; nf < 3; ++nf)
        #pragma unroll
        for (int mf = 0; mf < 2; ++mf)
          acc[mf][nf] = __builtin_amdgcn_mfma_f32_16x16x32_f16(af[mf], bcur[nf], acc[mf][nf], 0, 0, 0);
      #pragma unroll
      for (int nf = 0; nf < 3; ++nf) bcur[nf] = bnxt[nf];
    }
    __syncthreads();
  }

  // h1 tap phase: K=32 MFMA, k=0..15 from mini-halo (12 live); B zero for k>=16.
  {
    bool hiQ = quad >= 2;
    #pragma unroll
    for (int tap = 0; tap < 9; ++tap) {
      int dy = tap / 3, dx = tap - dy * 3;
      short8 bh[3];
      #pragma unroll
      for (int nf = 0; nf < 3; ++nf) {
        const short* whp = Wh + (size_t)((nf * 16 + ln15) * 9 + tap) * 16 + (quad & 1) * 8;
        bh[nf] = *(const short8*)(hiQ ? zp : whp);
      }
      short8 ah[2];
      #pragma unroll
      for (int mf = 0; mf < 2; ++mf)
        ah[mf] = *(const short8*)&h1h[((wr + dy) * 66 + wh * 32 + mf * 16 + ln15 + dx) * 16
                                      + (quad & 1) * 8];
      #pragma unroll
      for (int nf = 0; nf < 3; ++nf)
        #pragma unroll
        for (int mf = 0; mf < 2; ++mf)
          acc[mf][nf] = __builtin_amdgcn_mfma_f32_16x16x32_f16(ah[mf], bh[nf], acc[mf][nf], 0, 0, 0);
    }
  }
  __syncthreads();

  // z -> LDS (reuse halo; stride 49 avoids 4-way bank conflict), then gate pass
  float* zbuf = (float*)halo;
  #pragma unroll
  for (int mf = 0; mf < 2; ++mf)
    #pragma unroll
    for (int nf = 0; nf < 3; ++nf)
      #pragma unroll
      for (int r = 0; r < 4; ++r) {
        int pxl = wr * 64 + wh * 32 + mf * 16 + quad * 4 + r;
        zbuf[pxl * 49 + nf * 16 + ln15] = acc[mf][nf][r];
      }
  __syncthreads();

  #pragma unroll
  for (int k = 0; k < 6; ++k) {
    int id = k * 256 + tid;
    int hc = id >> 7, pxl = id & 127;
    float zi = zbuf[pxl * 49 + hc]      + Bc1[hc];
    float zf = zbuf[pxl * 49 + 12 + hc] + Bc1[12 + hc];
    float zo = zbuf[pxl * 49 + 24 + hc] + Bc1[24 + hc];
    float zg = zbuf[pxl * 49 + 36 + hc] + Bc1[36 + hc];
    int y = y0 + (pxl >> 6), x = pxl & 63;
    int pix = (b * 64 + y) * 64 + x;
    float cprev = C1[(size_t)pix * 12 + hc];
    float cn = sigf(zf) * cprev + sigf(zi) * tanhf(zg);
    float hn = sigf(zo) * tanhf(cn);
    C1[(size_t)pix * 12 + hc] = cn;
    H1wr[(size_t)pix * 16 + hc] = f2hs(hn);
    if (t == 11) {
      int oidx = (b * 12 + hc) * 4096 + y * 64 + x;
      if (flagv) ((float*)outp)[oidx] = hn;
      else ((short*)outp)[oidx] = f2bs(hn);
    }
  }
}

extern "C" void kernel_launch(void* const* d_in, const int* in_sizes, int n_in,
                              void* d_out, int out_size, void* d_ws, size_t ws_size,
                              hipStream_t stream) {
  const void* hist = d_in[0];                  // (16,12,4096,1)
  const void* W0 = d_in[2];                    // (512,129,3,3)
  const void* b0 = d_in[3];
  const void* W1 = d_in[4];                    // (48,140,3,3)
  const void* b1 = d_in[5];

  char* ws = (char*)d_ws;
  const size_t PszB = (size_t)16 * 4096 * CS * 2;     // 16,777,216
  short* P[2] = {(short*)ws, (short*)(ws + PszB)};
  float* C0 = (float*)(ws + 2 * PszB);                // 33,554,432
  const size_t C0e = 2 * PszB + 33554432;
  float* C1 = (float*)(ws + C0e);                     // 3,145,728
  const size_t C1e = C0e + 3145728;
  const size_t H1szB = (size_t)16 * 4096 * 16 * 2;    // 2,097,152
  short* H1[2] = {(short*)(ws + C1e), (short*)(ws + C1e + H1szB)};
  const size_t H1e = C1e + 2 * H1szB;
  short* zp = (short*)(ws + H1e);                     // 256 B zero page
  const size_t zpe = H1e + 256;                       // memset to here
  short* Xtap = (short*)(ws + zpe);                   // 12*65536*16*2 = 25,165,824
  const size_t Xte = zpe + (size_t)12 * 65536 * 16 * 2;
  short* Wp0 = (short*)(ws + Xte);                    // 512*1152*2 = 1,179,648
  const size_t W0e = Xte + (size_t)512 * KT0 * 2;
  short* Wx0 = (short*)(ws + W0e);                    // 512*16*2 = 16,384
  const size_t Wxe = W0e + 512 * 16 * 2;
  short* Wp1 = (short*)(ws + Wxe);                    // 48*1152*2 = 110,592
  const size_t W1e = Wxe + (size_t)48 * KT0 * 2;
  short* Wh1 = (short*)(ws + W1e);                    // 48*144*2 = 13,824
  const size_t Whe = W1e + 48 * 144 * 2;
  float* Bc0 = (float*)(ws + Whe);                    // 2048
  float* Bc1 = (float*)(ws + Whe + 2048);             // 192
  int* flag = (int*)(ws + Whe + 2048 + 192);          // total ~101 MiB

  hipMemsetAsync(ws, 0, zpe, stream);                 // P pair + C0 + C1 + H1 pair + zp
  detect_dtype<<<1, 64, 0, stream>>>((const unsigned short*)W0, flag);
  canon_b<<<3, 256, 0, stream>>>(b0, b1, Bc0, Bc1, flag);
  prep_w0<<<(512 * KT0 + 255) / 256, 256, 0, stream>>>(W0, Wp0, flag);
  prep_wx<<<32, 256, 0, stream>>>(W0, Wx0, flag);
  prep_w1<<<(48 * KT0 + 255) / 256, 256, 0, stream>>>(W1, Wp1, flag);
  prep_wh<<<27, 256, 0, stream>>>(W1, Wh1, flag);
  prep_xtap<<<3072, 256, 0, stream>>>(hist, Xtap, flag);

  for (int t = 0; t < 12; ++t) {
    gemm_gate0<<<2048, 256, 0, stream>>>(P[t & 1], P[(t + 1) & 1], Wp0, Wx0, Bc0, C0,
                                         Xtap, zp, t);
    gemm_gate1<<<512, 256, 0, stream>>>(P[(t + 1) & 1], H1[(t + 1) & 1], H1[t & 1],
                                        Wp1, Wh1, Bc1, C1, d_out, zp, flag, t);
  }
}

// Round 4
// 2220.733 us; speedup vs baseline: 1.1248x; 1.1194x over previous
//
#include <hip/hip_runtime.h>
#include <hip/hip_bf16.h>

// ConvLSTM (2 layers) on MI355X. R15 = R11 (proven 2198us) + tail-less DMA staging.
// R11 bug found: stage_row's scalar tail (register load -> ds_write) forced an
// in-order vmcnt drain of the just-issued global_load_lds DMAs INSIDE every stage,
// serializing DMA latency with compute (MfmaUtil stuck at 25%). R12-R14 (fusion,
// swizzles, dead-K removal) all bounced off this and regressed; fully reverted.
// Fix: halo rows padded to 5*1024B so staging is 5 wave-level DMAs, zero register
// loads (OOB/pad lanes read the zero page). The __syncthreads drain now sits after
// the 9-tap compute, so DMA latency is covered.
// Packed tensor P (B,64,64,160) fp16: [x(1), h0(128), h1(12), pad(19)].
// Geometry = R6/R11: 256-thr blocks, wave tile 64x64, acc 4x4, 1-tap B reg prefetch.
// LDS: dbuf 2*4 rows * 2560 shorts = 40960 B.

typedef __attribute__((ext_vector_type(8))) short short8;
typedef __attribute__((ext_vector_type(4))) float float4v;

#define CS 160
#define KTOT 1440         // 9*160
#define RSTR 2560         // LDS halo row stride (shorts) = 5 * 64 lanes * 8
#define BSTR 10240        // LDS buffer stride (shorts) = 4 * RSTR

__device__ __forceinline__ float sigf(float x) { return 1.f / (1.f + __expf(-x)); }
__device__ __forceinline__ short f2hs(float v) {
  _Float16 h = (_Float16)v;
  return *(short*)&h;
}
__device__ __forceinline__ float hs2f(short s) {
  _Float16 h; *(short*)&h = s; return (float)h;
}
__device__ __forceinline__ float bs2f(short s) {
  __hip_bfloat16 h; *(short*)&h = s; return __bfloat162float(h);
}
__device__ __forceinline__ short f2bs(float v) {
  __hip_bfloat16 h = __float2bfloat16(v);
  return *(short*)&h;
}

// async 16B global->LDS; per-lane lds ptr must equal uniform_base + lane*16
__device__ __forceinline__ void async_ld16(const short* g, short* l) {
  __builtin_amdgcn_global_load_lds(
      (const __attribute__((address_space(1))) unsigned int*)g,
      (__attribute__((address_space(3))) unsigned int*)l, 16, 0, 0);
}

// Stage one halo row (66 px x 32 ch) into LDS at dstRow (row-major, 32ch/px),
// 5 wave-level DMAs, NO register loads (no vmcnt drain inside the stage).
// e = j*64+lane; e<264: px=e>>2 (0..65), v=e&3; e>=264: pad, reads zero page.
__device__ __forceinline__ void stage_row(const short* __restrict__ rowPtr, bool rowOK,
                                          short* dstRow, int lane,
                                          const short* __restrict__ zp) {
  #pragma unroll
  for (int j = 0; j < 5; ++j) {
    int e = j * 64 + lane;
    int px = e >> 2, v = e & 3;
    int xx = px - 1;
    bool ok = rowOK && (px < 66) && (xx >= 0) && (xx < 64);
    const short* g = ok ? (rowPtr + (size_t)xx * CS + v * 8) : zp;
    async_ld16(g, dstRow + e * 8);
  }
}

// ---- dtype detect: fp32 low-halves have uniform bits[14:7]; bf16 weights cluster ----
__global__ void detect_dtype(const unsigned short* __restrict__ w0, int* __restrict__ flag) {
  int lane = threadIdx.x;
  int cnt = 0;
  for (int i = 0; i < 4; ++i) {
    unsigned short u = w0[2 * (lane + 64 * i)];
    int e = (u >> 7) & 0xFF;
    unsigned long long b = __ballot(e >= 0xC0);
    cnt += __popcll(b);
  }
  if (lane == 0) *flag = (cnt > 32) ? 1 : 0;   // 1 = fp32 inputs
}

// ---- canonicalize x -> fp16 shorts (bf16->fp16 exact; sanitized) ----
__global__ void canon_x(const void* __restrict__ hist, short* __restrict__ Xc,
                        const int* __restrict__ flag) {
  int i = blockIdx.x * 256 + threadIdx.x;      // < 786432
  float v = (*flag) ? ((const float*)hist)[i] : bs2f(((const short*)hist)[i]);
  if (!isfinite(v) || fabsf(v) > 1e4f) v = 0.f;
  Xc[i] = f2hs(v);
}

__global__ void canon_b(const void* __restrict__ b0, const void* __restrict__ b1,
                        float* __restrict__ Bc0, float* __restrict__ Bc1,
                        const int* __restrict__ flag) {
  int i = blockIdx.x * 256 + threadIdx.x;
  int fl = *flag;
  if (i < 512) {
    float v = fl ? ((const float*)b0)[i] : bs2f(((const short*)b0)[i]);
    if (!isfinite(v) || fabsf(v) > 1e4f) v = 0.f;
    Bc0[i] = v;
  } else if (i < 560) {
    int j = i - 512;
    float v = fl ? ((const float*)b1)[j] : bs2f(((const short*)b1)[j]);
    if (!isfinite(v) || fabsf(v) > 1e4f) v = 0.f;
    Bc1[j] = v;
  }
}

// layer0 W0 (512,129,3,3) -> fp16 Wp[co][tap*160+c]: P-ch 0=x, 1..128=h0, else 0.
__global__ void prep_w0(const void* __restrict__ W0, short* __restrict__ Wp,
                        const int* __restrict__ flag) {
  int i = blockIdx.x * 256 + threadIdx.x;
  if (i >= 512 * KTOT) return;
  int fl = *flag;
  int co = i / KTOT, k = i - co * KTOT;
  int tap = k / CS, c = k - tap * CS;
  int ci = -1;
  if (c == 0) ci = 0;
  else if (c <= 128) ci = c;
  float w = 0.f;
  if (ci >= 0) {
    int widx = (co * 129 + ci) * 9 + tap;
    w = fl ? ((const float*)W0)[widx] : bs2f(((const short*)W0)[widx]);
    if (!isfinite(w) || fabsf(w) > 1e4f) w = 0.f;
  }
  Wp[i] = f2hs(w);
}

// layer1 W1 (48,140,3,3) -> fp16: P-ch 1..128=h0, 129..140=h1, else 0.
__global__ void prep_w1(const void* __restrict__ W1, short* __restrict__ Wp,
                        const int* __restrict__ flag) {
  int i = blockIdx.x * 256 + threadIdx.x;
  if (i >= 48 * KTOT) return;
  int fl = *flag;
  int co = i / KTOT, k = i - co * KTOT;
  int tap = k / CS, c = k - tap * CS;
  int ci = -1;
  if (c >= 1 && c <= 140) ci = c - 1;
  float w = 0.f;
  if (ci >= 0) {
    int widx = (co * 140 + ci) * 9 + tap;
    w = fl ? ((const float*)W1)[widx] : bs2f(((const short*)W1)[widx]);
    if (!isfinite(w) || fabsf(w) > 1e4f) w = 0.f;
  }
  Wp[i] = f2hs(w);
}

__global__ void fill_x0(const short* __restrict__ Xc, short* __restrict__ P0) {
  int p = blockIdx.x * 256 + threadIdx.x;      // b*4096 + pix
  int b = p >> 12, pix = p & 4095;
  P0[(size_t)p * CS] = Xc[b * 12 * 4096 + pix];
}

// ---- layer 0: M=128px (2 rows) x N=128co (4 gates x 32 hc). Grid = 4 nt * 512 mt. ----
__global__ __launch_bounds__(256, 2) void gemm_gate0(
    const short* __restrict__ Pcur, short* __restrict__ Pnext,
    const short* __restrict__ Wp, const float* __restrict__ Bc0,
    float* __restrict__ C0, const short* __restrict__ Xc,
    const short* __restrict__ zp, int t) {
  int bx = blockIdx.x;
  int nt = bx >> 9, mt = bx & 511;             // consecutive blocks share nt (weight L2 reuse)
  int b = mt >> 5, y0 = (mt & 31) * 2;
  int tid = threadIdx.x, wave = tid >> 6, lane = tid & 63;
  int ln15 = lane & 15, quad = lane >> 4;
  int wm = wave & 1, wn = wave >> 1;
  int hc = nt * 32 + wn * 16 + ln15;

  __shared__ __align__(16) short halo[2 * BSTR];   // dbuf, 40960 B

  float4v acc[4][4];
  #pragma unroll
  for (int i = 0; i < 4; ++i)
    #pragma unroll
    for (int j = 0; j < 4; ++j) acc[i][j] = (float4v){0.f, 0.f, 0.f, 0.f};

  // B frag addr (g, tap, c0): wbase + g*128*KTOT + tap*CS + c0
  const short* wbase = Wp + (size_t)hc * KTOT + quad * 8;
  short8 bcur[4], bnxt[4];
  #pragma unroll
  for (int g = 0; g < 4; ++g)
    bcur[g] = *(const short8*)(wbase + (size_t)g * 128 * KTOT);

  int yy = y0 - 1 + wave;
  bool rowOK = (yy >= 0) && (yy < 64);
  const short* rowBase = Pcur + (size_t)((b * 64 + yy) * 64) * CS;

  stage_row(rowBase, rowOK, halo + wave * RSTR, lane, zp);
  __syncthreads();

  for (int ch = 0; ch < 5; ++ch) {
    int c0 = ch * 32;
    const short* cur = halo + (ch & 1) * BSTR;
    if (ch < 4)
      stage_row(rowBase + c0 + 32, rowOK, halo + ((ch + 1) & 1) * BSTR + wave * RSTR,
                lane, zp);
    #pragma unroll
    for (int tap = 0; tap < 9; ++tap) {
      int dy = tap / 3, dx = tap - dy * 3;
      // prefetch next tap's (or next chunk's tap-0) B fragments
      int ntap = (tap < 8) ? tap + 1 : 0;
      int nc0 = (tap < 8) ? c0 : ((ch < 4) ? c0 + 32 : c0);
      #pragma unroll
      for (int g = 0; g < 4; ++g)
        bnxt[g] = *(const short8*)(wbase + (size_t)g * 128 * KTOT + ntap * CS + nc0);

      short8 af[4];
      #pragma unroll
      for (int mf = 0; mf < 4; ++mf)
        af[mf] = *(const short8*)&cur[(wm + dy) * RSTR + (mf * 16 + ln15 + dx) * 32 + quad * 8];
      #pragma unroll
      for (int g = 0; g < 4; ++g)
        #pragma unroll
        for (int mf = 0; mf < 4; ++mf)
          acc[mf][g] = __builtin_amdgcn_mfma_f32_16x16x32_f16(af[mf], bcur[g], acc[mf][g], 0, 0, 0);
      #pragma unroll
      for (int g = 0; g < 4; ++g) bcur[g] = bnxt[g];
    }
    __syncthreads();
  }

  // epilogue: all 4 gates in-register per (pix,hc)
  float bi = Bc0[hc], bff = Bc0[128 + hc], bo = Bc0[256 + hc], bg = Bc0[384 + hc];
  int rowPix = (b * 64 + y0 + wm) * 64;
  #pragma unroll
  for (int mf = 0; mf < 4; ++mf) {
    #pragma unroll
    for (int r = 0; r < 4; ++r) {
      int x = mf * 16 + quad * 4 + r;          // C/D row = quad*4 + reg
      int pix = rowPix + x;
      float zi = acc[mf][0][r] + bi;
      float zf = acc[mf][1][r] + bff;
      float zo = acc[mf][2][r] + bo;
      float zg = acc[mf][3][r] + bg;
      float cprev = C0[(size_t)pix * 128 + hc];
      float cn = sigf(zf) * cprev + sigf(zi) * tanhf(zg);
      float hn = sigf(zo) * tanhf(cn);
      C0[(size_t)pix * 128 + hc] = cn;
      Pnext[(size_t)pix * CS + 1 + hc] = f2hs(hn);
    }
  }
  if (nt == 0 && t < 11 && tid < 128) {
    int rr = tid >> 6, x = tid & 63;
    int yw = y0 + rr;
    Pnext[(size_t)((b * 64 + yw) * 64 + x) * CS] = Xc[(b * 12 + t + 1) * 4096 + yw * 64 + x];
  }
}

// ---- layer 1: M=128px (2 rows) x N=48co. Grid 512. B register-prefetch. ----
__global__ __launch_bounds__(256, 2) void gemm_gate1(
    const short* __restrict__ Prd, short* __restrict__ Pwr,
    const short* __restrict__ Wp, const float* __restrict__ Bc1,
    float* __restrict__ C1, void* __restrict__ outp,
    const short* __restrict__ zp, const int* __restrict__ flagp, int t) {
  int bid = blockIdx.x;                        // 0..511
  int b = bid >> 5, y0 = (bid & 31) * 2;
  int tid = threadIdx.x, wave = tid >> 6, lane = tid & 63;
  int ln15 = lane & 15, quad = lane >> 4;
  int wr = wave >> 1, wh = wave & 1;
  int flagv = *flagp;

  __shared__ __align__(16) short halo[2 * BSTR];   // 40960 B

  float4v acc[2][3];
  #pragma unroll
  for (int i = 0; i < 2; ++i)
    #pragma unroll
    for (int j = 0; j < 3; ++j) acc[i][j] = (float4v){0.f, 0.f, 0.f, 0.f};

  int yy = y0 - 1 + wave;
  bool rowOK = (yy >= 0) && (yy < 64);
  const short* rowBase = Prd + (size_t)((b * 64 + yy) * 64) * CS;

  const short* wbase = Wp + (size_t)ln15 * KTOT + quad * 8;
  short8 bcur[3], bnxt[3];
  #pragma unroll
  for (int nf = 0; nf < 3; ++nf)
    bcur[nf] = *(const short8*)(wbase + (size_t)nf * 16 * KTOT);

  stage_row(rowBase, rowOK, halo + wave * RSTR, lane, zp);
  __syncthreads();

  for (int ch = 0; ch < 5; ++ch) {
    int c0 = ch * 32;
    const short* cur = halo + (ch & 1) * BSTR;
    if (ch < 4)
      stage_row(rowBase + c0 + 32, rowOK, halo + ((ch + 1) & 1) * BSTR + wave * RSTR,
                lane, zp);
    #pragma unroll
    for (int tap = 0; tap < 9; ++tap) {
      int dy = tap / 3, dx = tap - dy * 3;
      int ntap = (tap < 8) ? tap + 1 : 0;
      int nc0 = (tap < 8) ? c0 : ((ch < 4) ? c0 + 32 : c0);
      #pragma unroll
      for (int nf = 0; nf < 3; ++nf)
        bnxt[nf] = *(const short8*)(wbase + (size_t)nf * 16 * KTOT + ntap * CS + nc0);

      short8 af[2];
      #pragma unroll
      for (int mf = 0; mf < 2; ++mf)
        af[mf] = *(const short8*)&cur[(wr + dy) * RSTR + (wh * 32 + mf * 16 + ln15 + dx) * 32
                                      + quad * 8];
      #pragma unroll
      for (int nf = 0; nf < 3; ++nf)
        #pragma unroll
        for (int mf = 0; mf < 2; ++mf)
          acc[mf][nf] = __builtin_amdgcn_mfma_f32_16x16x32_f16(af[mf], bcur[nf], acc[mf][nf], 0, 0, 0);
      #pragma unroll
      for (int nf = 0; nf < 3; ++nf) bcur[nf] = bnxt[nf];
    }
    __syncthreads();
  }

  // z -> LDS (reuse halo: 128*48 fp32 = 24576 B), then gate pass
  float* zbuf = (float*)halo;
  #pragma unroll
  for (int mf = 0; mf < 2; ++mf)
    #pragma unroll
    for (int nf = 0; nf < 3; ++nf)
      #pragma unroll
      for (int r = 0; r < 4; ++r) {
        int pxl = wr * 64 + wh * 32 + mf * 16 + quad * 4 + r;
        zbuf[pxl * 48 + nf * 16 + ln15] = acc[mf][nf][r];
      }
  __syncthreads();

  #pragma unroll
  for (int k = 0; k < 6; ++k) {
    int id = k * 256 + tid;
    int hc = id >> 7, pxl = id & 127;
    float zi = zbuf[pxl * 48 + hc]      + Bc1[hc];
    float zf = zbuf[pxl * 48 + 12 + hc] + Bc1[12 + hc];
    float zo = zbuf[pxl * 48 + 24 + hc] + Bc1[24 + hc];
    float zg = zbuf[pxl * 48 + 36 + hc] + Bc1[36 + hc];
    int y = y0 + (pxl >> 6), x = pxl & 63;
    int pix = (b * 64 + y) * 64 + x;
    float cprev = C1[(size_t)pix * 12 + hc];
    float cn = sigf(zf) * cprev + sigf(zi) * tanhf(zg);
    float hn = sigf(zo) * tanhf(cn);
    C1[(size_t)pix * 12 + hc] = cn;
    Pwr[(size_t)pix * CS + 129 + hc] = f2hs(hn);
    if (t == 11) {
      int oidx = (b * 12 + hc) * 4096 + y * 64 + x;
      if (flagv) ((float*)outp)[oidx] = hn;
      else ((short*)outp)[oidx] = f2bs(hn);
    }
  }
}

extern "C" void kernel_launch(void* const* d_in, const int* in_sizes, int n_in,
                              void* d_out, int out_size, void* d_ws, size_t ws_size,
                              hipStream_t stream) {
  const void* hist = d_in[0];                  // (16,12,4096,1)
  const void* W0 = d_in[2];                    // (512,129,3,3)
  const void* b0 = d_in[3];
  const void* W1 = d_in[4];                    // (48,140,3,3)
  const void* b1 = d_in[5];

  char* ws = (char*)d_ws;
  const size_t PszB = (size_t)16 * 4096 * CS * 2;     // 20,971,520
  short* P[2] = {(short*)ws, (short*)(ws + PszB)};
  float* C0 = (float*)(ws + 2 * PszB);                // 33,554,432
  const size_t C0e = 2 * PszB + 33554432;
  float* C1 = (float*)(ws + C0e);                     // 3,145,728
  const size_t C1e = C0e + 3145728;
  short* zp = (short*)(ws + C1e);                     // 256 B zero page
  const size_t zpe = C1e + 256;
  short* Xc = (short*)(ws + zpe);                     // 1,572,864
  const size_t Xce = zpe + 1572864;
  short* Wp0 = (short*)(ws + Xce);                    // 512*1440*2 = 1,474,560
  const size_t W0e = Xce + (size_t)512 * KTOT * 2;
  short* Wp1 = (short*)(ws + W0e);                    // 48*1440*2 = 138,240
  const size_t W1e = W0e + (size_t)48 * KTOT * 2;
  float* Bc0 = (float*)(ws + W1e);                    // 2048
  float* Bc1 = (float*)(ws + W1e + 2048);             // 192
  int* flag = (int*)(ws + W1e + 2048 + 192);          // total ~82 MiB

  hipMemsetAsync(ws, 0, zpe, stream);                 // P pair + C0 + C1 + zero page
  detect_dtype<<<1, 64, 0, stream>>>((const unsigned short*)W0, flag);
  canon_x<<<3072, 256, 0, stream>>>(hist, Xc, flag);
  canon_b<<<3, 256, 0, stream>>>(b0, b1, Bc0, Bc1, flag);
  prep_w0<<<(512 * KTOT + 255) / 256, 256, 0, stream>>>(W0, Wp0, flag);
  prep_w1<<<(48 * KTOT + 255) / 256, 256, 0, stream>>>(W1, Wp1, flag);
  fill_x0<<<256, 256, 0, stream>>>(Xc, P[0]);

  for (int t = 0; t < 12; ++t) {
    gemm_gate0<<<2048, 256, 0, stream>>>(P[t & 1], P[(t + 1) & 1], Wp0, Bc0, C0, Xc, zp, t);
    gemm_gate1<<<512, 256, 0, stream>>>(P[(t + 1) & 1], P[t & 1], Wp1, Bc1, C1,
                                        d_out, zp, flag, t);
  }
}

// Round 5
// 2116.967 us; speedup vs baseline: 1.1799x; 1.0490x over previous
//
#include <hip/hip_runtime.h>
#include <hip/hip_bf16.h>

// ConvLSTM (2 layers) on MI355X. R16 = R15 + nt-grouped XCD stripe swizzle.
// Counter-derived: R11 FETCH=100MB (P halo read by ~3 XCDs each, 63MB vs 21MB unique);
// R14's swizzle cut FETCH to 72 but spread nt over XCDs -> Pnext 128B-line false
// sharing (WRITE 60->82). R16 groups all 4 nt of an mt on ONE XCD and stripes mt:
// XCD x owns mt in [64x,64x+64) = 2 batches of P (2.6MB, L2-fit, reused 12x).
// Staging: tail-less DMA rows (R15), 5 wave-DMAs/row, zero page for OOB/pad.
// Packed tensor P (B,64,64,160) fp16: [x(1), h0(128), h1(12), pad(19)].
// Geometry = R6/R11: 256-thr blocks, wave tile 64x64, acc 4x4, 1-tap B reg prefetch.
// LDS: dbuf 2*4 rows * 2560 shorts = 40960 B.

typedef __attribute__((ext_vector_type(8))) short short8;
typedef __attribute__((ext_vector_type(4))) float float4v;

#define CS 160
#define KTOT 1440         // 9*160
#define RSTR 2560         // LDS halo row stride (shorts) = 5 * 64 lanes * 8
#define BSTR 10240        // LDS buffer stride (shorts) = 4 * RSTR

__device__ __forceinline__ float sigf(float x) { return 1.f / (1.f + __expf(-x)); }
__device__ __forceinline__ short f2hs(float v) {
  _Float16 h = (_Float16)v;
  return *(short*)&h;
}
__device__ __forceinline__ float hs2f(short s) {
  _Float16 h; *(short*)&h = s; return (float)h;
}
__device__ __forceinline__ float bs2f(short s) {
  __hip_bfloat16 h; *(short*)&h = s; return __bfloat162float(h);
}
__device__ __forceinline__ short f2bs(float v) {
  __hip_bfloat16 h = __float2bfloat16(v);
  return *(short*)&h;
}

// async 16B global->LDS; per-lane lds ptr must equal uniform_base + lane*16
__device__ __forceinline__ void async_ld16(const short* g, short* l) {
  __builtin_amdgcn_global_load_lds(
      (const __attribute__((address_space(1))) unsigned int*)g,
      (__attribute__((address_space(3))) unsigned int*)l, 16, 0, 0);
}

// Stage one halo row (66 px x 32 ch) into LDS at dstRow (row-major, 32ch/px),
// 5 wave-level DMAs, NO register loads (no vmcnt drain inside the stage).
__device__ __forceinline__ void stage_row(const short* __restrict__ rowPtr, bool rowOK,
                                          short* dstRow, int lane,
                                          const short* __restrict__ zp) {
  #pragma unroll
  for (int j = 0; j < 5; ++j) {
    int e = j * 64 + lane;
    int px = e >> 2, v = e & 3;
    int xx = px - 1;
    bool ok = rowOK && (px < 66) && (xx >= 0) && (xx < 64);
    const short* g = ok ? (rowPtr + (size_t)xx * CS + v * 8) : zp;
    async_ld16(g, dstRow + e * 8);
  }
}

// ---- dtype detect: fp32 low-halves have uniform bits[14:7]; bf16 weights cluster ----
__global__ void detect_dtype(const unsigned short* __restrict__ w0, int* __restrict__ flag) {
  int lane = threadIdx.x;
  int cnt = 0;
  for (int i = 0; i < 4; ++i) {
    unsigned short u = w0[2 * (lane + 64 * i)];
    int e = (u >> 7) & 0xFF;
    unsigned long long b = __ballot(e >= 0xC0);
    cnt += __popcll(b);
  }
  if (lane == 0) *flag = (cnt > 32) ? 1 : 0;   // 1 = fp32 inputs
}

// ---- canonicalize x -> fp16 shorts (bf16->fp16 exact; sanitized) ----
__global__ void canon_x(const void* __restrict__ hist, short* __restrict__ Xc,
                        const int* __restrict__ flag) {
  int i = blockIdx.x * 256 + threadIdx.x;      // < 786432
  float v = (*flag) ? ((const float*)hist)[i] : bs2f(((const short*)hist)[i]);
  if (!isfinite(v) || fabsf(v) > 1e4f) v = 0.f;
  Xc[i] = f2hs(v);
}

__global__ void canon_b(const void* __restrict__ b0, const void* __restrict__ b1,
                        float* __restrict__ Bc0, float* __restrict__ Bc1,
                        const int* __restrict__ flag) {
  int i = blockIdx.x * 256 + threadIdx.x;
  int fl = *flag;
  if (i < 512) {
    float v = fl ? ((const float*)b0)[i] : bs2f(((const short*)b0)[i]);
    if (!isfinite(v) || fabsf(v) > 1e4f) v = 0.f;
    Bc0[i] = v;
  } else if (i < 560) {
    int j = i - 512;
    float v = fl ? ((const float*)b1)[j] : bs2f(((const short*)b1)[j]);
    if (!isfinite(v) || fabsf(v) > 1e4f) v = 0.f;
    Bc1[j] = v;
  }
}

// layer0 W0 (512,129,3,3) -> fp16 Wp[co][tap*160+c]: P-ch 0=x, 1..128=h0, else 0.
__global__ void prep_w0(const void* __restrict__ W0, short* __restrict__ Wp,
                        const int* __restrict__ flag) {
  int i = blockIdx.x * 256 + threadIdx.x;
  if (i >= 512 * KTOT) return;
  int fl = *flag;
  int co = i / KTOT, k = i - co * KTOT;
  int tap = k / CS, c = k - tap * CS;
  int ci = -1;
  if (c == 0) ci = 0;
  else if (c <= 128) ci = c;
  float w = 0.f;
  if (ci >= 0) {
    int widx = (co * 129 + ci) * 9 + tap;
    w = fl ? ((const float*)W0)[widx] : bs2f(((const short*)W0)[widx]);
    if (!isfinite(w) || fabsf(w) > 1e4f) w = 0.f;
  }
  Wp[i] = f2hs(w);
}

// layer1 W1 (48,140,3,3) -> fp16: P-ch 1..128=h0, 129..140=h1, else 0.
__global__ void prep_w1(const void* __restrict__ W1, short* __restrict__ Wp,
                        const int* __restrict__ flag) {
  int i = blockIdx.x * 256 + threadIdx.x;
  if (i >= 48 * KTOT) return;
  int fl = *flag;
  int co = i / KTOT, k = i - co * KTOT;
  int tap = k / CS, c = k - tap * CS;
  int ci = -1;
  if (c >= 1 && c <= 140) ci = c - 1;
  float w = 0.f;
  if (ci >= 0) {
    int widx = (co * 140 + ci) * 9 + tap;
    w = fl ? ((const float*)W1)[widx] : bs2f(((const short*)W1)[widx]);
    if (!isfinite(w) || fabsf(w) > 1e4f) w = 0.f;
  }
  Wp[i] = f2hs(w);
}

__global__ void fill_x0(const short* __restrict__ Xc, short* __restrict__ P0) {
  int p = blockIdx.x * 256 + threadIdx.x;      // b*4096 + pix
  int b = p >> 12, pix = p & 4095;
  P0[(size_t)p * CS] = Xc[b * 12 * 4096 + pix];
}

// ---- layer 0: M=128px (2 rows) x N=128co (4 gates x 32 hc). Grid = 4 nt * 512 mt. ----
__global__ __launch_bounds__(256, 2) void gemm_gate0(
    const short* __restrict__ Pcur, short* __restrict__ Pnext,
    const short* __restrict__ Wp, const float* __restrict__ Bc0,
    float* __restrict__ C0, const short* __restrict__ Xc,
    const short* __restrict__ zp, int t) {
  // nt-grouped XCD stripe swizzle: hw maps pbx%8 -> XCD. XCD x owns mt in
  // [64x, 64x+64) (= 2 batches of P, L2-fit) for ALL 4 nt (no cross-XCD
  // false sharing of Pnext h0 lines). Bijective: (xcd,i) <-> (nt,mt).
  int pbx = blockIdx.x;
  int xcd = pbx & 7, i = pbx >> 3;
  int mt = xcd * 64 + (i & 63);
  int nt = i >> 6;
  int b = mt >> 5, y0 = (mt & 31) * 2;
  int tid = threadIdx.x, wave = tid >> 6, lane = tid & 63;
  int ln15 = lane & 15, quad = lane >> 4;
  int wm = wave & 1, wn = wave >> 1;
  int hc = nt * 32 + wn * 16 + ln15;

  __shared__ __align__(16) short halo[2 * BSTR];   // dbuf, 40960 B

  float4v acc[4][4];
  #pragma unroll
  for (int i2 = 0; i2 < 4; ++i2)
    #pragma unroll
    for (int j = 0; j < 4; ++j) acc[i2][j] = (float4v){0.f, 0.f, 0.f, 0.f};

  // B frag addr (g, tap, c0): wbase + g*128*KTOT + tap*CS + c0
  const short* wbase = Wp + (size_t)hc * KTOT + quad * 8;
  short8 bcur[4], bnxt[4];
  #pragma unroll
  for (int g = 0; g < 4; ++g)
    bcur[g] = *(const short8*)(wbase + (size_t)g * 128 * KTOT);

  int yy = y0 - 1 + wave;
  bool rowOK = (yy >= 0) && (yy < 64);
  const short* rowBase = Pcur + (size_t)((b * 64 + yy) * 64) * CS;

  stage_row(rowBase, rowOK, halo + wave * RSTR, lane, zp);
  __syncthreads();

  for (int ch = 0; ch < 5; ++ch) {
    int c0 = ch * 32;
    const short* cur = halo + (ch & 1) * BSTR;
    if (ch < 4)
      stage_row(rowBase + c0 + 32, rowOK, halo + ((ch + 1) & 1) * BSTR + wave * RSTR,
                lane, zp);
    #pragma unroll
    for (int tap = 0; tap < 9; ++tap) {
      int dy = tap / 3, dx = tap - dy * 3;
      // prefetch next tap's (or next chunk's tap-0) B fragments
      int ntap = (tap < 8) ? tap + 1 : 0;
      int nc0 = (tap < 8) ? c0 : ((ch < 4) ? c0 + 32 : c0);
      #pragma unroll
      for (int g = 0; g < 4; ++g)
        bnxt[g] = *(const short8*)(wbase + (size_t)g * 128 * KTOT + ntap * CS + nc0);

      short8 af[4];
      #pragma unroll
      for (int mf = 0; mf < 4; ++mf)
        af[mf] = *(const short8*)&cur[(wm + dy) * RSTR + (mf * 16 + ln15 + dx) * 32 + quad * 8];
      #pragma unroll
      for (int g = 0; g < 4; ++g)
        #pragma unroll
        for (int mf = 0; mf < 4; ++mf)
          acc[mf][g] = __builtin_amdgcn_mfma_f32_16x16x32_f16(af[mf], bcur[g], acc[mf][g], 0, 0, 0);
      #pragma unroll
      for (int g = 0; g < 4; ++g) bcur[g] = bnxt[g];
    }
    __syncthreads();
  }

  // epilogue: all 4 gates in-register per (pix,hc)
  float bi = Bc0[hc], bff = Bc0[128 + hc], bo = Bc0[256 + hc], bg = Bc0[384 + hc];
  int rowPix = (b * 64 + y0 + wm) * 64;
  #pragma unroll
  for (int mf = 0; mf < 4; ++mf) {
    #pragma unroll
    for (int r = 0; r < 4; ++r) {
      int x = mf * 16 + quad * 4 + r;          // C/D row = quad*4 + reg
      int pix = rowPix + x;
      float zi = acc[mf][0][r] + bi;
      float zf = acc[mf][1][r] + bff;
      float zo = acc[mf][2][r] + bo;
      float zg = acc[mf][3][r] + bg;
      float cprev = C0[(size_t)pix * 128 + hc];
      float cn = sigf(zf) * cprev + sigf(zi) * tanhf(zg);
      float hn = sigf(zo) * tanhf(cn);
      C0[(size_t)pix * 128 + hc] = cn;
      Pnext[(size_t)pix * CS + 1 + hc] = f2hs(hn);
    }
  }
  if (nt == 0 && t < 11 && tid < 128) {
    int rr = tid >> 6, x = tid & 63;
    int yw = y0 + rr;
    Pnext[(size_t)((b * 64 + yw) * 64 + x) * CS] = Xc[(b * 12 + t + 1) * 4096 + yw * 64 + x];
  }
}

// ---- layer 1: M=128px (2 rows) x N=48co. Grid 512. B register-prefetch. ----
__global__ __launch_bounds__(256, 2) void gemm_gate1(
    const short* __restrict__ Prd, short* __restrict__ Pwr,
    const short* __restrict__ Wp, const float* __restrict__ Bc1,
    float* __restrict__ C1, void* __restrict__ outp,
    const short* __restrict__ zp, const int* __restrict__ flagp, int t) {
  // XCD stripe swizzle: XCD x owns bid in [64x, 64x+64) = 2 batches (L2-fit halos).
  int pbx = blockIdx.x;
  int bid = (pbx & 7) * 64 + (pbx >> 3);
  int b = bid >> 5, y0 = (bid & 31) * 2;
  int tid = threadIdx.x, wave = tid >> 6, lane = tid & 63;
  int ln15 = lane & 15, quad = lane >> 4;
  int wr = wave >> 1, wh = wave & 1;
  int flagv = *flagp;

  __shared__ __align__(16) short halo[2 * BSTR];   // 40960 B

  float4v acc[2][3];
  #pragma unroll
  for (int i = 0; i < 2; ++i)
    #pragma unroll
    for (int j = 0; j < 3; ++j) acc[i][j] = (float4v){0.f, 0.f, 0.f, 0.f};

  int yy = y0 - 1 + wave;
  bool rowOK = (yy >= 0) && (yy < 64);
  const short* rowBase = Prd + (size_t)((b * 64 + yy) * 64) * CS;

  const short* wbase = Wp + (size_t)ln15 * KTOT + quad * 8;
  short8 bcur[3], bnxt[3];
  #pragma unroll
  for (int nf = 0; nf < 3; ++nf)
    bcur[nf] = *(const short8*)(wbase + (size_t)nf * 16 * KTOT);

  stage_row(rowBase, rowOK, halo + wave * RSTR, lane, zp);
  __syncthreads();

  for (int ch = 0; ch < 5; ++ch) {
    int c0 = ch * 32;
    const short* cur = halo + (ch & 1) * BSTR;
    if (ch < 4)
      stage_row(rowBase + c0 + 32, rowOK, halo + ((ch + 1) & 1) * BSTR + wave * RSTR,
                lane, zp);
    #pragma unroll
    for (int tap = 0; tap < 9; ++tap) {
      int dy = tap / 3, dx = tap - dy * 3;
      int ntap = (tap < 8) ? tap + 1 : 0;
      int nc0 = (tap < 8) ? c0 : ((ch < 4) ? c0 + 32 : c0);
      #pragma unroll
      for (int nf = 0; nf < 3; ++nf)
        bnxt[nf] = *(const short8*)(wbase + (size_t)nf * 16 * KTOT + ntap * CS + nc0);

      short8 af[2];
      #pragma unroll
      for (int mf = 0; mf < 2; ++mf)
        af[mf] = *(const short8*)&cur[(wr + dy) * RSTR + (wh * 32 + mf * 16 + ln15 + dx) * 32
                                      + quad * 8];
      #pragma unroll
      for (int nf = 0; nf < 3; ++nf)
        #pragma unroll
        for (int mf = 0; mf < 2; ++mf)
          acc[mf][nf] = __builtin_amdgcn_mfma_f32_16x16x32_f16(af[mf], bcur[nf], acc[mf][nf], 0, 0, 0);
      #pragma unroll
      for (int nf = 0; nf < 3; ++nf) bcur[nf] = bnxt[nf];
    }
    __syncthreads();
  }

  // z -> LDS (reuse halo: 128*48 fp32 = 24576 B), then gate pass
  float* zbuf = (float*)halo;
  #pragma unroll
  for (int mf = 0; mf < 2; ++mf)
    #pragma unroll
    for (int nf = 0; nf < 3; ++nf)
      #pragma unroll
      for (int r = 0; r < 4; ++r) {
        int pxl = wr * 64 + wh * 32 + mf * 16 + quad * 4 + r;
        zbuf[pxl * 48 + nf * 16 + ln15] = acc[mf][nf][r];
      }
  __syncthreads();

  #pragma unroll
  for (int k = 0; k < 6; ++k) {
    int id = k * 256 + tid;
    int hc = id >> 7, pxl = id & 127;
    float zi = zbuf[pxl * 48 + hc]      + Bc1[hc];
    float zf = zbuf[pxl * 48 + 12 + hc] + Bc1[12 + hc];
    float zo = zbuf[pxl * 48 + 24 + hc] + Bc1[24 + hc];
    float zg = zbuf[pxl * 48 + 36 + hc] + Bc1[36 + hc];
    int y = y0 + (pxl >> 6), x = pxl & 63;
    int pix = (b * 64 + y) * 64 + x;
    float cprev = C1[(size_t)pix * 12 + hc];
    float cn = sigf(zf) * cprev + sigf(zi) * tanhf(zg);
    float hn = sigf(zo) * tanhf(cn);
    C1[(size_t)pix * 12 + hc] = cn;
    Pwr[(size_t)pix * CS + 129 + hc] = f2hs(hn);
    if (t == 11) {
      int oidx = (b * 12 + hc) * 4096 + y * 64 + x;
      if (flagv) ((float*)outp)[oidx] = hn;
      else ((short*)outp)[oidx] = f2bs(hn);
    }
  }
}

extern "C" void kernel_launch(void* const* d_in, const int* in_sizes, int n_in,
                              void* d_out, int out_size, void* d_ws, size_t ws_size,
                              hipStream_t stream) {
  const void* hist = d_in[0];                  // (16,12,4096,1)
  const void* W0 = d_in[2];                    // (512,129,3,3)
  const void* b0 = d_in[3];
  const void* W1 = d_in[4];                    // (48,140,3,3)
  const void* b1 = d_in[5];

  char* ws = (char*)d_ws;
  const size_t PszB = (size_t)16 * 4096 * CS * 2;     // 20,971,520
  short* P[2] = {(short*)ws, (short*)(ws + PszB)};
  float* C0 = (float*)(ws + 2 * PszB);                // 33,554,432
  const size_t C0e = 2 * PszB + 33554432;
  float* C1 = (float*)(ws + C0e);                     // 3,145,728
  const size_t C1e = C0e + 3145728;
  short* zp = (short*)(ws + C1e);                     // 256 B zero page
  const size_t zpe = C1e + 256;
  short* Xc = (short*)(ws + zpe);                     // 1,572,864
  const size_t Xce = zpe + 1572864;
  short* Wp0 = (short*)(ws + Xce);                    // 512*1440*2 = 1,474,560
  const size_t W0e = Xce + (size_t)512 * KTOT * 2;
  short* Wp1 = (short*)(ws + W0e);                    // 48*1440*2 = 138,240
  const size_t W1e = W0e + (size_t)48 * KTOT * 2;
  float* Bc0 = (float*)(ws + W1e);                    // 2048
  float* Bc1 = (float*)(ws + W1e + 2048);             // 192
  int* flag = (int*)(ws + W1e + 2048 + 192);          // total ~82 MiB

  hipMemsetAsync(ws, 0, zpe, stream);                 // P pair + C0 + C1 + zero page
  detect_dtype<<<1, 64, 0, stream>>>((const unsigned short*)W0, flag);
  canon_x<<<3072, 256, 0, stream>>>(hist, Xc, flag);
  canon_b<<<3, 256, 0, stream>>>(b0, b1, Bc0, Bc1, flag);
  prep_w0<<<(512 * KTOT + 255) / 256, 256, 0, stream>>>(W0, Wp0, flag);
  prep_w1<<<(48 * KTOT + 255) / 256, 256, 0, stream>>>(W1, Wp1, flag);
  fill_x0<<<256, 256, 0, stream>>>(Xc, P[0]);

  for (int t = 0; t < 12; ++t) {
    gemm_gate0<<<2048, 256, 0, stream>>>(P[t & 1], P[(t + 1) & 1], Wp0, Bc0, C0, Xc, zp, t);
    gemm_gate1<<<512, 256, 0, stream>>>(P[(t + 1) & 1], P[t & 1], Wp1, Bc1, C1,
                                        d_out, zp, flag, t);
  }
}